// Round 5
// baseline (111.420 us; speedup 1.0000x reference)
//
#include <hip/hip_runtime.h>
#include <math.h>

typedef __bf16 bf16;
typedef __bf16 bf16x8 __attribute__((ext_vector_type(8)));
typedef float  f32x16 __attribute__((ext_vector_type(16)));

#define D_INC 16
#define NODES 32
#define HID   32
#define HS    48
#define WSZ   48
#define NPX   (HS*WSZ)     // 2304
#define H_IN  96
#define W_IN  96
#define N_B   32

#define MP_BLOCKS   1152   // 32*48*48*4 / 256
#define WPRE_BLOCKS 640    // 163840 / 256

// ---------------- Kernel P+W merged ----------------
// blocks [0, MP_BLOCKS): maxpool 3x3 s2 p1 -> Pg (N,48,48,16ch) bf16,
//   one thread per (pixel, 4-channel quad): 36 loads/thread
// blocks [MP_BLOCKS, ...): Wkron precompute
__global__ __launch_bounds__(256) void pre_kernel(
    const float* __restrict__ x, bf16* __restrict__ Pg,
    const float* __restrict__ S, const float* __restrict__ W1,
    const float* __restrict__ b1, bf16* __restrict__ Wp)
{
    if (blockIdx.x < MP_BLOCKS) {
        int idx = blockIdx.x * 256 + threadIdx.x;   // (n, r, c, q) q = ch-quad
        int q = idx & 3;
        int c = (idx >> 2) % WSZ;
        int t = (idx >> 2) / WSZ;
        int r = t % HS;
        int n = t / HS;

        const float* xb = x + ((size_t)(n * D_INC + q * 4)) * (H_IN * W_IN);

        float m0 = -INFINITY, m1 = -INFINITY, m2 = -INFINITY, m3 = -INFINITY;
        #pragma unroll
        for (int dr = 0; dr < 3; ++dr) {
            int xr = 2 * r - 1 + dr;
            if (xr < 0) continue;                   // xr <= 95 always
            #pragma unroll
            for (int dc = 0; dc < 3; ++dc) {
                int xc = 2 * c - 1 + dc;
                if (xc < 0) continue;               // xc <= 95 always
                const float* p = xb + xr * W_IN + xc;
                m0 = fmaxf(m0, p[0 * H_IN * W_IN]);
                m1 = fmaxf(m1, p[1 * H_IN * W_IN]);
                m2 = fmaxf(m2, p[2 * H_IN * W_IN]);
                m3 = fmaxf(m3, p[3 * H_IN * W_IN]);
            }
        }
        union { bf16 h[4]; uint2 u; } v;
        v.h[0] = (bf16)m0; v.h[1] = (bf16)m1; v.h[2] = (bf16)m2; v.h[3] = (bf16)m3;
        *(uint2*)(Pg + (size_t)idx * 4) = v.u;
    } else {
        // Wkron[o][s][qp][h][j] = S[o,d,t]*W1[o,d,h], k = 16s+8qp+j
        // k==144 -> b1[o,h]; k>144 -> 0. Lane-linear for A-fragment loads.
        int idx = (blockIdx.x - MP_BLOCKS) * 256 + threadIdx.x;
        if (idx >= NODES * 10 * 2 * HID * 8) return;
        int j  = idx & 7;
        int h  = (idx >> 3) & 31;
        int qp = (idx >> 8) & 1;
        int os = idx >> 9;
        int s  = os % 10;
        int o  = os / 10;
        int k  = 16 * s + 8 * qp + j;
        float v = 0.f;
        if (k < 144) {
            int t = k >> 4;
            int d = k & 15;
            v = S[(o * D_INC + d) * 9 + t] * W1[(o * D_INC + d) * HID + h];
        } else if (k == 144) {
            v = b1[o * HID + h];
        }
        Wp[idx] = (bf16)v;
    }
}

// ---------------- Kernel G: fused (conv+MLP1) GEMM via MFMA + MLP2 epilogue ----------------
// grid (9 px-chunks, 32 batch, 8 node-quads of 4); block 512 = 8 waves
// wave: ONE px-tile of 32 (VGPR ~110 -> 4 waves/SIMD, was ~190 -> 2)
__global__ __launch_bounds__(512, 4) void gemm_kernel(
    const bf16* __restrict__ Pg, const bf16* __restrict__ Wp,
    const float* __restrict__ W2, const float* __restrict__ b2,
    float* __restrict__ out)
{
    __shared__ __align__(16) bf16  Pl[8 * 50 * D_INC];   // 12.8 KB, [row][col][ch]
    __shared__ __align__(16) float W2l[4 * HID];         // 0.5 KB

    const int b    = blockIdx.x;            // px chunk: 256 px
    const int n    = blockIdx.y;
    const int ob   = blockIdx.z * 4;        // node base
    const int tid  = threadIdx.x;
    const int lane = tid & 63;
    const int w    = tid >> 6;              // 0..7
    const int ln31 = lane & 31;
    const int qp   = lane >> 5;

    const int px0     = b * 256;
    const int r_start = px0 / 48;           // chunk spans pool rows r_start..r_start+5

    const uint4 z4 = make_uint4(0u, 0u, 0u, 0u);

    // ---- stage P tile: 8 rows (r_start-1 .. r_start+6) x 48 cols x 16ch, OOB rows = 0
    for (int u = tid; u < 768; u += 512) {
        int half = u & 1;
        int colu = (u >> 1) % 48;
        int row  = (u >> 1) / 48;
        int pr   = r_start - 1 + row;
        uint4 v  = z4;
        if (pr >= 0 && pr < HS)
            v = *(const uint4*)(Pg + ((size_t)(n * HS + pr) * WSZ + colu) * D_INC + half * 8);
        *(uint4*)(Pl + (row * 50 + colu + 1) * D_INC + half * 8) = v;
    }
    if (tid < 32) {
        // halo cols 0 and 49 = 0 (conv zero padding)
        int row  = tid >> 2;
        int side = (tid >> 1) & 1;
        int half = tid & 1;
        *(uint4*)(Pl + (row * 50 + side * 49) * D_INC + half * 8) = z4;
        // W2 for this block's 4 nodes
        ((float4*)W2l)[tid] = ((const float4*)(W2 + ob * HID))[tid];
    }
    __syncthreads();

    // ---- this wave's pixel tile (32 px) ----
    const int px = px0 + w * 32 + ln31;
    const int r  = px / 48;
    const int c  = px - r * 48;
    const int rl = r - r_start;                      // 0..5; tap row in LDS = rl + di
    const int base_ad = ((rl * 50) + c) * 32 + qp * 16;  // byte addr of (di=0,dj=0,ch=8*qp)

    // ---- build B (pixel) fragments: lane holds U[k=16s+8qp+j][px], one ds_read_b128 each
    bf16x8 Bf[10];
    #pragma unroll
    for (int s = 0; s < 9; ++s) {
        const int di = s / 3, dj = s % 3;            // compile-time tap offsets
        Bf[s] = *(const bf16x8*)((const char*)Pl + base_ad + (di * 50 + dj) * 32);
    }
    {
        bf16x8 bias = {};
        if (qp == 0) bias[0] = (bf16)1.0f;           // k==144 constant-1 slot
        Bf[9] = bias;
    }

    // ---- node loop (4 nodes/block) ----
    for (int o4 = 0; o4 < 4; ++o4) {
        const int o = ob + o4;

        // A (weight) fragments: 10 coalesced dwordx4 from L2-resident Wkron
        const bf16* wp = Wp + (size_t)(o * 10) * 512 + lane * 8;
        bf16x8 Af[10];
        #pragma unroll
        for (int s = 0; s < 10; ++s)
            Af[s] = *(const bf16x8*)(wp + s * 512);

        f32x16 acc = {};
        #pragma unroll
        for (int s = 0; s < 10; ++s)
            acc = __builtin_amdgcn_mfma_f32_32x32x16_bf16(Af[s], Bf[s], acc, 0, 0, 0);

        // W2 per-lane regs AFTER the MFMA chain (keeps loop live-set small):
        // reg i -> h = (i&3) + 8*(i>>2) + 4*qp
        const float* w2b = W2l + o4 * HID + 4 * qp;
        float4 w2v0 = *(const float4*)(w2b);
        float4 w2v1 = *(const float4*)(w2b + 8);
        float4 w2v2 = *(const float4*)(w2b + 16);
        float4 w2v3 = *(const float4*)(w2b + 24);
        const float bb = b2[o];

        float part;
        part  = fmaxf(acc[0],  0.f) * w2v0.x;
        part  = fmaf(fmaxf(acc[1],  0.f), w2v0.y, part);
        part  = fmaf(fmaxf(acc[2],  0.f), w2v0.z, part);
        part  = fmaf(fmaxf(acc[3],  0.f), w2v0.w, part);
        part  = fmaf(fmaxf(acc[4],  0.f), w2v1.x, part);
        part  = fmaf(fmaxf(acc[5],  0.f), w2v1.y, part);
        part  = fmaf(fmaxf(acc[6],  0.f), w2v1.z, part);
        part  = fmaf(fmaxf(acc[7],  0.f), w2v1.w, part);
        part  = fmaf(fmaxf(acc[8],  0.f), w2v2.x, part);
        part  = fmaf(fmaxf(acc[9],  0.f), w2v2.y, part);
        part  = fmaf(fmaxf(acc[10], 0.f), w2v2.z, part);
        part  = fmaf(fmaxf(acc[11], 0.f), w2v2.w, part);
        part  = fmaf(fmaxf(acc[12], 0.f), w2v3.x, part);
        part  = fmaf(fmaxf(acc[13], 0.f), w2v3.y, part);
        part  = fmaf(fmaxf(acc[14], 0.f), w2v3.z, part);
        part  = fmaf(fmaxf(acc[15], 0.f), w2v3.w, part);
        float tot = part + __shfl_xor(part, 32);
        tot = fmaxf(tot + bb, 0.f);
        if (qp == 0)
            out[(size_t)(n * NODES + o) * NPX + px] = tot;
    }
}

extern "C" void kernel_launch(void* const* d_in, const int* in_sizes, int n_in,
                              void* d_out, int out_size, void* d_ws, size_t ws_size,
                              hipStream_t stream)
{
    const float* x  = (const float*)d_in[0];
    const float* S  = (const float*)d_in[1];
    const float* W1 = (const float*)d_in[2];
    const float* b1 = (const float*)d_in[3];
    const float* W2 = (const float*)d_in[4];
    const float* b2 = (const float*)d_in[5];
    float* out = (float*)d_out;

    bf16* Pg = (bf16*)d_ws;                                   // 2,359,296 B
    bf16* Wp = (bf16*)((char*)d_ws + (size_t)N_B * NPX * D_INC * 2);  // 327,680 B

    pre_kernel<<<MP_BLOCKS + WPRE_BLOCKS, 256, 0, stream>>>(x, Pg, S, W1, b1, Wp);

    dim3 grid(9, N_B, 8);
    gemm_kernel<<<grid, 512, 0, stream>>>(Pg, Wp, W2, b2, out);
}

// Round 6
// 104.472 us; speedup vs baseline: 1.0665x; 1.0665x over previous
//
#include <hip/hip_runtime.h>
#include <math.h>

typedef __bf16 bf16;
typedef __bf16 bf16x8 __attribute__((ext_vector_type(8)));
typedef float  f32x16 __attribute__((ext_vector_type(16)));

#define D_INC 16
#define NODES 32
#define HID   32
#define HS    48
#define WSZ   48
#define NPX   (HS*WSZ)     // 2304
#define H_IN  96
#define W_IN  96
#define N_B   32

#define MP_BLOCKS   1152   // 32*48*4*48 / 256
#define WPRE_BLOCKS 640    // 163840 / 256

// ---------------- Kernel P+W merged ----------------
// blocks [0, MP_BLOCKS): maxpool 3x3 s2 p1 -> Pg (N,48,48,16ch) bf16.
//   thread = (n, r, q, c) with c lane-fastest -> coalesced reads per plane row;
//   each thread does 4 channels (q = quad), 36 loads, scattered 8B store.
// blocks [MP_BLOCKS, ...): Wkron precompute
__global__ __launch_bounds__(256) void pre_kernel(
    const float* __restrict__ x, bf16* __restrict__ Pg,
    const float* __restrict__ S, const float* __restrict__ W1,
    const float* __restrict__ b1, bf16* __restrict__ Wp)
{
    if (blockIdx.x < MP_BLOCKS) {
        int idx = blockIdx.x * 256 + threadIdx.x;   // ((n*48+r)*4+q)*48+c
        int c  = idx % WSZ;
        int t  = idx / WSZ;
        int q  = t & 3;
        int rr = t >> 2;
        int r  = rr % HS;
        int n  = rr / HS;

        const float* xb = x + ((size_t)(n * D_INC + q * 4)) * (H_IN * W_IN);

        float m0 = -INFINITY, m1 = -INFINITY, m2 = -INFINITY, m3 = -INFINITY;
        #pragma unroll
        for (int dr = 0; dr < 3; ++dr) {
            int xr = 2 * r - 1 + dr;
            if (xr < 0) continue;                   // xr <= 95 always
            #pragma unroll
            for (int dc = 0; dc < 3; ++dc) {
                int xc = 2 * c - 1 + dc;
                if (xc < 0) continue;               // xc <= 95 always
                const float* p = xb + xr * W_IN + xc;
                m0 = fmaxf(m0, p[0 * H_IN * W_IN]);
                m1 = fmaxf(m1, p[1 * H_IN * W_IN]);
                m2 = fmaxf(m2, p[2 * H_IN * W_IN]);
                m3 = fmaxf(m3, p[3 * H_IN * W_IN]);
            }
        }
        union { bf16 h[4]; uint2 u; } v;
        v.h[0] = (bf16)m0; v.h[1] = (bf16)m1; v.h[2] = (bf16)m2; v.h[3] = (bf16)m3;
        // Pg layout: ((n*48+r)*48+c)*16 + ch, ch = 4q..4q+3
        *(uint2*)(Pg + ((size_t)((n * HS + r) * WSZ + c)) * D_INC + q * 4) = v.u;
    } else {
        // Wkron[o][s][qp][h][j] = S[o,d,t]*W1[o,d,h], k = 16s+8qp+j
        // k==144 -> b1[o,h]; k>144 -> 0. Lane-linear for A-fragment loads.
        int idx = (blockIdx.x - MP_BLOCKS) * 256 + threadIdx.x;
        if (idx >= NODES * 10 * 2 * HID * 8) return;
        int j  = idx & 7;
        int h  = (idx >> 3) & 31;
        int qp = (idx >> 8) & 1;
        int os = idx >> 9;
        int s  = os % 10;
        int o  = os / 10;
        int k  = 16 * s + 8 * qp + j;
        float v = 0.f;
        if (k < 144) {
            int t = k >> 4;
            int d = k & 15;
            v = S[(o * D_INC + d) * 9 + t] * W1[(o * D_INC + d) * HID + h];
        } else if (k == 144) {
            v = b1[o * HID + h];
        }
        Wp[idx] = (bf16)v;
    }
}

// ---------------- Kernel G: fused (conv+MLP1) GEMM via MFMA + MLP2 epilogue ----------------
// grid (9 px-chunks, 32 batch, 8 node-quads of 4); block 256 = 4 waves (R4 shape).
// wave: 2 px-tiles of 32, 2 independent MFMA chains.
// NEW: the 4 nodes' Wkron staged to LDS once -> inner-loop A-frags are ds_read_b128.
__global__ __launch_bounds__(256, 2) void gemm_kernel(
    const bf16* __restrict__ Pg, const bf16* __restrict__ Wp,
    const float* __restrict__ W2, const float* __restrict__ b2,
    float* __restrict__ out)
{
    __shared__ __align__(16) bf16  Pl[8 * 50 * D_INC];   // 12.8 KB, [row][col][ch]
    __shared__ __align__(16) bf16  Wl[4 * 10 * 512];     // 40 KB, node-quad Wkron
    __shared__ __align__(16) float W2l[4 * HID];         // 0.5 KB

    const int b    = blockIdx.x;            // px chunk: 256 px
    const int n    = blockIdx.y;
    const int ob   = blockIdx.z * 4;        // node base
    const int tid  = threadIdx.x;
    const int lane = tid & 63;
    const int w    = tid >> 6;              // 0..3
    const int ln31 = lane & 31;
    const int qp   = lane >> 5;

    const int px0     = b * 256;
    const int r_start = px0 / 48;           // chunk spans pool rows r_start..r_start+5

    const uint4 z4 = make_uint4(0u, 0u, 0u, 0u);

    // ---- stage Wkron for nodes ob..ob+3: 2560 uint4, perfectly linear ----
    {
        const uint4* src = (const uint4*)(Wp + (size_t)ob * 10 * 512);
        uint4*       dst = (uint4*)Wl;
        #pragma unroll
        for (int i = 0; i < 10; ++i)
            dst[i * 256 + tid] = src[i * 256 + tid];
    }

    // ---- stage P tile: 8 rows (r_start-1 .. r_start+6) x 48 cols x 16ch, OOB rows = 0
    for (int u = tid; u < 768; u += 256) {
        int half = u & 1;
        int colu = (u >> 1) % 48;
        int row  = (u >> 1) / 48;
        int pr   = r_start - 1 + row;
        uint4 v  = z4;
        if (pr >= 0 && pr < HS)
            v = *(const uint4*)(Pg + ((size_t)(n * HS + pr) * WSZ + colu) * D_INC + half * 8);
        *(uint4*)(Pl + (row * 50 + colu + 1) * D_INC + half * 8) = v;
    }
    if (tid < 32) {
        // halo cols 0 and 49 = 0 (conv zero padding)
        int row  = tid >> 2;
        int side = (tid >> 1) & 1;
        int half = tid & 1;
        *(uint4*)(Pl + (row * 50 + side * 49) * D_INC + half * 8) = z4;
        // W2 for this block's 4 nodes
        ((float4*)W2l)[tid] = ((const float4*)(W2 + ob * HID))[tid];
    }
    __syncthreads();

    // ---- per-wave pixel fragment bases (2 tiles of 32 px) ----
    int base_ad[2];
    int pxg[2];
    #pragma unroll
    for (int t = 0; t < 2; ++t) {
        int px = px0 + w * 64 + t * 32 + ln31;
        int r  = px / 48;
        int c  = px - r * 48;
        int rl = r - r_start;                     // 0..5; tap row in LDS = rl + di
        base_ad[t] = ((rl * 50) + c) * 32 + qp * 16;   // byte addr of (di=0,dj=0,ch=8*qp)
        pxg[t] = px;
    }

    // ---- build B (pixel) fragments: lane holds U[k=16s+8qp+j][px], one ds_read_b128 each
    bf16x8 Bf[2][10];
    #pragma unroll
    for (int t = 0; t < 2; ++t) {
        #pragma unroll
        for (int s = 0; s < 9; ++s) {
            const int di = s / 3, dj = s % 3;     // compile-time tap offsets
            Bf[t][s] = *(const bf16x8*)((const char*)Pl + base_ad[t] + (di * 50 + dj) * 32);
        }
        bf16x8 bias = {};
        if (qp == 0) bias[0] = (bf16)1.0f;        // k==144 constant-1 slot
        Bf[t][9] = bias;
    }

    // ---- node loop (4 nodes/block), A-frags from LDS ----
    for (int o4 = 0; o4 < 4; ++o4) {
        const int o = ob + o4;

        bf16x8 Af[10];
        #pragma unroll
        for (int s = 0; s < 10; ++s)
            Af[s] = *(const bf16x8*)(Wl + (o4 * 10 + s) * 512 + lane * 8);

        f32x16 acc0 = {};
        f32x16 acc1 = {};
        #pragma unroll
        for (int s = 0; s < 10; ++s) {
            acc0 = __builtin_amdgcn_mfma_f32_32x32x16_bf16(Af[s], Bf[0][s], acc0, 0, 0, 0);
            acc1 = __builtin_amdgcn_mfma_f32_32x32x16_bf16(Af[s], Bf[1][s], acc1, 0, 0, 0);
        }

        // W2 per-lane regs: reg i -> h = (i&3) + 8*(i>>2) + 4*qp
        const float* w2b = W2l + o4 * HID + 4 * qp;
        float4 w2v0 = *(const float4*)(w2b);
        float4 w2v1 = *(const float4*)(w2b + 8);
        float4 w2v2 = *(const float4*)(w2b + 16);
        float4 w2v3 = *(const float4*)(w2b + 24);
        const float bb = b2[o];

        #pragma unroll
        for (int t = 0; t < 2; ++t) {
            const f32x16 a = t ? acc1 : acc0;
            float part;
            part  = fmaxf(a[0],  0.f) * w2v0.x;
            part  = fmaf(fmaxf(a[1],  0.f), w2v0.y, part);
            part  = fmaf(fmaxf(a[2],  0.f), w2v0.z, part);
            part  = fmaf(fmaxf(a[3],  0.f), w2v0.w, part);
            part  = fmaf(fmaxf(a[4],  0.f), w2v1.x, part);
            part  = fmaf(fmaxf(a[5],  0.f), w2v1.y, part);
            part  = fmaf(fmaxf(a[6],  0.f), w2v1.z, part);
            part  = fmaf(fmaxf(a[7],  0.f), w2v1.w, part);
            part  = fmaf(fmaxf(a[8],  0.f), w2v2.x, part);
            part  = fmaf(fmaxf(a[9],  0.f), w2v2.y, part);
            part  = fmaf(fmaxf(a[10], 0.f), w2v2.z, part);
            part  = fmaf(fmaxf(a[11], 0.f), w2v2.w, part);
            part  = fmaf(fmaxf(a[12], 0.f), w2v3.x, part);
            part  = fmaf(fmaxf(a[13], 0.f), w2v3.y, part);
            part  = fmaf(fmaxf(a[14], 0.f), w2v3.z, part);
            part  = fmaf(fmaxf(a[15], 0.f), w2v3.w, part);
            float tot = part + __shfl_xor(part, 32);
            tot = fmaxf(tot + bb, 0.f);
            if (qp == 0)
                out[(size_t)(n * NODES + o) * NPX + pxg[t]] = tot;
        }
    }
}

extern "C" void kernel_launch(void* const* d_in, const int* in_sizes, int n_in,
                              void* d_out, int out_size, void* d_ws, size_t ws_size,
                              hipStream_t stream)
{
    const float* x  = (const float*)d_in[0];
    const float* S  = (const float*)d_in[1];
    const float* W1 = (const float*)d_in[2];
    const float* b1 = (const float*)d_in[3];
    const float* W2 = (const float*)d_in[4];
    const float* b2 = (const float*)d_in[5];
    float* out = (float*)d_out;

    bf16* Pg = (bf16*)d_ws;                                   // 2,359,296 B
    bf16* Wp = (bf16*)((char*)d_ws + (size_t)N_B * NPX * D_INC * 2);  // 327,680 B

    pre_kernel<<<MP_BLOCKS + WPRE_BLOCKS, 256, 0, stream>>>(x, Pg, S, W1, b1, Wp);

    dim3 grid(9, N_B, 8);
    gemm_kernel<<<grid, 256, 0, stream>>>(Pg, Wp, W2, b2, out);
}